// Round 1
// baseline (1052.640 us; speedup 1.0000x reference)
//
#include <hip/hip_runtime.h>
#include <hip/hip_bf16.h>

// ---------------------------------------------------------------------------
// GNN Residual Feature Extractor
//   x = embed(type features)                       [N,32]
//   x1 = gcn(x, W1)+b1                             [N,64]
//   h  = relu(gcn(relu(x1),W2)+b2)                 [N,128]
//   h  = relu(gcn(h,W3)+b3) + x1                   [N,64]
//   out = segment_mean(h, batch)                   [100,64]
// gcn aggregation commutes with weight multiply; aggregate on narrow side.
// ---------------------------------------------------------------------------

#define THREADS 256

// ---------------- degree count ----------------
__global__ __launch_bounds__(THREADS)
void k_count(const int* __restrict__ dst, int* __restrict__ cnt, int e) {
    int i = blockIdx.x * THREADS + threadIdx.x;
    if (i < e) atomicAdd(&cnt[dst[i]], 1);
}

// ---------------- scan (3 kernels) ----------------
__global__ __launch_bounds__(THREADS)
void k_block_sums(const int* __restrict__ cnt, int* __restrict__ bsums, int n) {
    __shared__ int lds[THREADS];
    int i = blockIdx.x * THREADS + threadIdx.x;
    lds[threadIdx.x] = (i < n) ? cnt[i] : 0;
    __syncthreads();
    for (int off = THREADS / 2; off > 0; off >>= 1) {
        if (threadIdx.x < off) lds[threadIdx.x] += lds[threadIdx.x + off];
        __syncthreads();
    }
    if (threadIdx.x == 0) bsums[blockIdx.x] = lds[0];
}

__global__ __launch_bounds__(512)
void k_scan_bsums(int* __restrict__ bsums, int nblk) {
    __shared__ int lds[512];
    int t = threadIdx.x;
    int v = (t < nblk) ? bsums[t] : 0;
    lds[t] = v;
    __syncthreads();
    for (int off = 1; off < 512; off <<= 1) {
        int a = (t >= off) ? lds[t - off] : 0;
        __syncthreads();
        lds[t] += a;
        __syncthreads();
    }
    if (t < nblk) bsums[t] = lds[t] - v;  // exclusive
}

__global__ __launch_bounds__(THREADS)
void k_scan_final(const int* __restrict__ cnt, const int* __restrict__ bexcl,
                  int* __restrict__ rowptr, int* __restrict__ cursor,
                  int n, int e_total) {
    __shared__ int lds[THREADS];
    int t = threadIdx.x;
    int i = blockIdx.x * THREADS + t;
    int v = (i < n) ? cnt[i] : 0;
    lds[t] = v;
    __syncthreads();
    for (int off = 1; off < THREADS; off <<= 1) {
        int a = (t >= off) ? lds[t - off] : 0;
        __syncthreads();
        lds[t] += a;
        __syncthreads();
    }
    if (i < n) {
        int excl = bexcl[blockIdx.x] + lds[t] - v;
        rowptr[i] = excl;
        cursor[i] = excl;
    }
    if (i == 0) rowptr[n] = e_total;
}

// ---------------- dinv ----------------
__global__ __launch_bounds__(THREADS)
void k_dinv(const int* __restrict__ cnt, float* __restrict__ dinv, int n) {
    int i = blockIdx.x * THREADS + threadIdx.x;
    if (i < n) dinv[i] = rsqrtf((float)cnt[i] + 1.0f);
}

// ---------------- CSR fill ----------------
__global__ __launch_bounds__(THREADS)
void k_fill(const int* __restrict__ src, const int* __restrict__ dst,
            int* __restrict__ cursor, int* __restrict__ srcs, int e) {
    int i = blockIdx.x * THREADS + threadIdx.x;
    if (i < e) {
        int d = dst[i];
        int pos = atomicAdd(&cursor[d], 1);
        srcs[pos] = src[i];
    }
}

// ---------------- embedding: x[idx[r]] = f[r] @ W + b ----------------
template <int K>
__global__ __launch_bounds__(THREADS)
void k_embed(const float* __restrict__ f, const float* __restrict__ W,
             const float* __restrict__ b, const int* __restrict__ idx,
             int rows, float* __restrict__ x) {
    int g = blockIdx.x * THREADS + threadIdx.x;
    int r = g >> 5, c = g & 31;
    if (r >= rows) return;
    float a = b[c];
#pragma unroll
    for (int k = 0; k < K; ++k) a += f[r * K + k] * W[k * 32 + c];
    x[(size_t)idx[r] * 32 + c] = a;
}

// ---------------- gather aggregation ----------------
// out[i] = dv_i * ( dv_i * t(tbl[i]) + sum_j dinv[s_j] * t(tbl[s_j]) )
// t() = optional relu on read. Optional epilogue: +bias, relu, +resid.
template <int C, bool INRELU, bool HASBIAS, bool OUTRELU, bool HASRES>
__global__ __launch_bounds__(THREADS)
void k_gather(const float* __restrict__ tbl, const int* __restrict__ rowptr,
              const int* __restrict__ srcs, const float* __restrict__ dinv,
              const float* __restrict__ bias, const float* __restrict__ resid,
              float* __restrict__ out, int n) {
    int gt = blockIdx.x * THREADS + threadIdx.x;
    int node = gt >> 6;
    int lane = threadIdx.x & 63;
    if (node >= n) return;
    float dv = dinv[node];
    int beg = rowptr[node], end = rowptr[node + 1];

    if (C == 64) {
        float xv = tbl[(size_t)node * 64 + lane];
        if (INRELU) xv = fmaxf(xv, 0.f);
        float acc = dv * xv;
        int j = beg;
        for (; j + 4 <= end; j += 4) {
            int s0 = srcs[j], s1 = srcs[j + 1], s2 = srcs[j + 2], s3 = srcs[j + 3];
            float d0 = dinv[s0], d1 = dinv[s1], d2 = dinv[s2], d3 = dinv[s3];
            float v0 = tbl[(size_t)s0 * 64 + lane];
            float v1 = tbl[(size_t)s1 * 64 + lane];
            float v2 = tbl[(size_t)s2 * 64 + lane];
            float v3 = tbl[(size_t)s3 * 64 + lane];
            if (INRELU) {
                v0 = fmaxf(v0, 0.f); v1 = fmaxf(v1, 0.f);
                v2 = fmaxf(v2, 0.f); v3 = fmaxf(v3, 0.f);
            }
            acc += d0 * v0; acc += d1 * v1; acc += d2 * v2; acc += d3 * v3;
        }
        for (; j < end; ++j) {
            int s = srcs[j];
            float v = tbl[(size_t)s * 64 + lane];
            if (INRELU) v = fmaxf(v, 0.f);
            acc += dinv[s] * v;
        }
        float r = dv * acc;
        if (HASBIAS) r += bias[lane];
        if (OUTRELU) r = fmaxf(r, 0.f);
        if (HASRES) r += resid[(size_t)node * 64 + lane];
        out[(size_t)node * 64 + lane] = r;
    } else {  // C == 32 : two half-waves take alternate edges
        int col = lane & 31, half = lane >> 5;
        float acc = 0.f;
        for (int j = beg + half; j < end; j += 2) {
            int s = srcs[j];
            float v = tbl[(size_t)s * 32 + col];
            if (INRELU) v = fmaxf(v, 0.f);
            acc += dinv[s] * v;
        }
        acc += __shfl_down(acc, 32, 64);
        if (half == 0) {
            float xv = tbl[(size_t)node * 32 + col];
            if (INRELU) xv = fmaxf(xv, 0.f);
            float r = dv * (acc + dv * xv);
            if (HASBIAS) r += bias[col];
            if (OUTRELU) r = fmaxf(r, 0.f);
            if (HASRES) r += resid[(size_t)node * 32 + col];
            out[(size_t)node * 32 + col] = r;
        }
    }
}

// ---------------- dense matmul: out[N,FOUT] = in[N,FIN] @ W + b ----------------
// thread-per-row; W^T staged in LDS, broadcast float4 reads; x row in registers.
template <int FIN, int FOUT, bool HASBIAS, bool OUTRELU>
__global__ __launch_bounds__(THREADS)
void k_mm(const float* __restrict__ xin, const float* __restrict__ W,
          const float* __restrict__ bias, float* __restrict__ out, int nrows) {
    constexpr int FINQ = FIN / 4;
    __shared__ float wlds[FOUT * FIN];
    int tid = threadIdx.x;
    for (int i = tid; i < FIN * FOUT; i += THREADS) {
        int k = i / FOUT, c = i % FOUT;
        wlds[c * FIN + k] = W[i];  // store W^T
    }
    __syncthreads();
    int row = blockIdx.x * THREADS + tid;
    if (row >= nrows) return;

    float4 xreg[FINQ];
    const float4* xr = reinterpret_cast<const float4*>(xin + (size_t)row * FIN);
#pragma unroll
    for (int q = 0; q < FINQ; ++q) xreg[q] = xr[q];

    const float4* w4 = reinterpret_cast<const float4*>(wlds);
    for (int c0 = 0; c0 < FOUT; c0 += 4) {
        float a0 = HASBIAS ? bias[c0 + 0] : 0.f;
        float a1 = HASBIAS ? bias[c0 + 1] : 0.f;
        float a2 = HASBIAS ? bias[c0 + 2] : 0.f;
        float a3 = HASBIAS ? bias[c0 + 3] : 0.f;
#pragma unroll
        for (int q = 0; q < FINQ; ++q) {
            float4 xv = xreg[q];
            float4 w0 = w4[(c0 + 0) * FINQ + q];
            float4 w1 = w4[(c0 + 1) * FINQ + q];
            float4 w2 = w4[(c0 + 2) * FINQ + q];
            float4 w3 = w4[(c0 + 3) * FINQ + q];
            a0 += xv.x * w0.x + xv.y * w0.y + xv.z * w0.z + xv.w * w0.w;
            a1 += xv.x * w1.x + xv.y * w1.y + xv.z * w1.z + xv.w * w1.w;
            a2 += xv.x * w2.x + xv.y * w2.y + xv.z * w2.z + xv.w * w2.w;
            a3 += xv.x * w3.x + xv.y * w3.y + xv.z * w3.z + xv.w * w3.w;
        }
        if (OUTRELU) {
            a0 = fmaxf(a0, 0.f); a1 = fmaxf(a1, 0.f);
            a2 = fmaxf(a2, 0.f); a3 = fmaxf(a3, 0.f);
        }
        float4 o = {a0, a1, a2, a3};
        *reinterpret_cast<float4*>(out + (size_t)row * FOUT + c0) = o;
    }
}

// ---------------- segment mean pool ----------------
__global__ __launch_bounds__(THREADS)
void k_pool(const float* __restrict__ h, const int* __restrict__ batch,
            float* __restrict__ sums, float* __restrict__ cnts, int n) {
    int c = threadIdx.x & 63;
    int rq = threadIdx.x >> 6;  // 0..3
    int r0 = blockIdx.x * THREADS;
    int rend = min(r0 + THREADS, n);
    int curg = -1;
    float acc = 0.f, cacc = 0.f;
    for (int r = r0 + rq; r < rend; r += 4) {
        int g = batch[r];
        if (g != curg) {
            if (curg >= 0) {
                atomicAdd(&sums[(size_t)curg * 64 + c], acc);
                if (c == 0) atomicAdd(&cnts[curg], cacc);
            }
            curg = g; acc = 0.f; cacc = 0.f;
        }
        acc += h[(size_t)r * 64 + c];
        cacc += 1.f;
    }
    if (curg >= 0) {
        atomicAdd(&sums[(size_t)curg * 64 + c], acc);
        if (c == 0) atomicAdd(&cnts[curg], cacc);
    }
}

__global__ __launch_bounds__(THREADS)
void k_div(const float* __restrict__ sums, const float* __restrict__ cnts,
           float* __restrict__ out, int total) {
    int i = blockIdx.x * THREADS + threadIdx.x;
    if (i < total) out[i] = sums[i] / cnts[i >> 6];
}

// ---------------------------------------------------------------------------
static inline size_t alignup(size_t v) { return (v + 255) & ~(size_t)255; }

extern "C" void kernel_launch(void* const* d_in, const int* in_sizes, int n_in,
                              void* d_out, int out_size, void* d_ws, size_t ws_size,
                              hipStream_t stream) {
    const float* ev_f  = (const float*)d_in[0];
    const float* cs_f  = (const float*)d_in[1];
    const float* tr_f  = (const float*)d_in[2];
    const float* env_f = (const float*)d_in[3];
    const int*   ei    = (const int*)d_in[4];
    const int*   ev_i  = (const int*)d_in[5];
    const int*   cs_i  = (const int*)d_in[6];
    const int*   tr_i  = (const int*)d_in[7];
    const int*   env_i = (const int*)d_in[8];
    const int*   batch = (const int*)d_in[9];
    const float* W_ev = (const float*)d_in[10]; const float* b_ev = (const float*)d_in[11];
    const float* W_cs = (const float*)d_in[12]; const float* b_cs = (const float*)d_in[13];
    const float* W_tr = (const float*)d_in[14]; const float* b_tr = (const float*)d_in[15];
    const float* W_env= (const float*)d_in[16]; const float* b_env= (const float*)d_in[17];
    const float* W1 = (const float*)d_in[18]; const float* b1 = (const float*)d_in[19];
    const float* W2 = (const float*)d_in[20]; const float* b2 = (const float*)d_in[21];
    const float* W3 = (const float*)d_in[22]; const float* b3 = (const float*)d_in[23];

    const int E_ = in_sizes[4] / 2;
    const int N_ = in_sizes[9];
    const int n_ev  = in_sizes[5];
    const int n_cs  = in_sizes[6];
    const int n_tr  = in_sizes[7];
    const int n_env = in_sizes[8];
    const int ngr   = out_size / 64;  // 100 graphs

    const int* e_src = ei;
    const int* e_dst = ei + E_;

    // ---- workspace carve-up ----
    char* p = (char*)d_ws;
    int*   cnt    = (int*)p;    p += alignup((size_t)N_ * 4);
    float* dinv   = (float*)p;  p += alignup((size_t)N_ * 4);
    int*   rowptr = (int*)p;    p += alignup(((size_t)N_ + 1) * 4);
    int*   cursor = (int*)p;    p += alignup((size_t)N_ * 4);
    int*   bsums  = (int*)p;    p += alignup((size_t)512 * 4);
    int*   srcs   = (int*)p;    p += alignup((size_t)E_ * 4);
    float* x      = (float*)p;  p += alignup((size_t)N_ * 32 * 4);
    float* x1     = (float*)p;  p += alignup((size_t)N_ * 64 * 4);
    float* bufB   = (float*)p;  p += alignup((size_t)N_ * 64 * 4);
    float* bufA   = (float*)p;  p += alignup((size_t)N_ * 128 * 4);
    float* sums   = (float*)p;  p += alignup((size_t)ngr * 64 * 4);
    float* cnts   = (float*)p;  p += alignup((size_t)ngr * 4);

    const int nblk  = (N_ + THREADS - 1) / THREADS;          // 391
    const int eblk  = (E_ + THREADS - 1) / THREADS;          // 12500
    const int gblk  = ((size_t)N_ * 64 + THREADS - 1) / THREADS;  // wave per node

    // ---- zero the accumulated buffers (fresh every call) ----
    hipMemsetAsync(cnt,  0, (size_t)N_ * 4, stream);
    hipMemsetAsync(sums, 0, (size_t)ngr * 64 * 4, stream);
    hipMemsetAsync(cnts, 0, (size_t)ngr * 4, stream);

    // ---- degree / CSR build ----
    k_count<<<eblk, THREADS, 0, stream>>>(e_dst, cnt, E_);
    k_block_sums<<<nblk, THREADS, 0, stream>>>(cnt, bsums, N_);
    k_scan_bsums<<<1, 512, 0, stream>>>(bsums, nblk);
    k_scan_final<<<nblk, THREADS, 0, stream>>>(cnt, bsums, rowptr, cursor, N_, E_);
    k_dinv<<<nblk, THREADS, 0, stream>>>(cnt, dinv, N_);
    k_fill<<<eblk, THREADS, 0, stream>>>(e_src, e_dst, cursor, srcs, E_);

    // ---- embeddings -> x [N,32] ----
    k_embed<6><<<((size_t)n_ev  * 32 + THREADS - 1) / THREADS, THREADS, 0, stream>>>(ev_f,  W_ev,  b_ev,  ev_i,  n_ev,  x);
    k_embed<4><<<((size_t)n_cs  * 32 + THREADS - 1) / THREADS, THREADS, 0, stream>>>(cs_f,  W_cs,  b_cs,  cs_i,  n_cs,  x);
    k_embed<2><<<((size_t)n_tr  * 32 + THREADS - 1) / THREADS, THREADS, 0, stream>>>(tr_f,  W_tr,  b_tr,  tr_i,  n_tr,  x);
    k_embed<5><<<((size_t)n_env * 32 + THREADS - 1) / THREADS, THREADS, 0, stream>>>(env_f, W_env, b_env, env_i, n_env, x);

    // ---- conv1: agg(x) @ W1 + b1 -> x1 ----
    k_gather<32, false, false, false, false><<<gblk, THREADS, 0, stream>>>(
        x, rowptr, srcs, dinv, nullptr, nullptr, bufB, N_);
    k_mm<32, 64, true, false><<<nblk, THREADS, 0, stream>>>(bufB, W1, b1, x1, N_);

    // ---- conv2: relu( agg(relu(x1)) @ W2 + b2 ) -> bufA [N,128] ----
    k_gather<64, true, false, false, false><<<gblk, THREADS, 0, stream>>>(
        x1, rowptr, srcs, dinv, nullptr, nullptr, bufB, N_);
    k_mm<64, 128, true, true><<<nblk, THREADS, 0, stream>>>(bufB, W2, b2, bufA, N_);

    // ---- conv3: relu( agg(bufA @ W3) + b3 ) + x1 -> bufA [N,64] ----
    k_mm<128, 64, false, false><<<nblk, THREADS, 0, stream>>>(bufA, W3, nullptr, bufB, N_);
    k_gather<64, false, true, true, true><<<gblk, THREADS, 0, stream>>>(
        bufB, rowptr, srcs, dinv, b3, x1, bufA, N_);

    // ---- pool ----
    k_pool<<<nblk, THREADS, 0, stream>>>(bufA, batch, sums, cnts, N_);
    k_div<<<(out_size + THREADS - 1) / THREADS, THREADS, 0, stream>>>(sums, cnts, (float*)d_out, out_size);
}

// Round 2
// 871.345 us; speedup vs baseline: 1.2081x; 1.2081x over previous
//
#include <hip/hip_runtime.h>
#include <hip/hip_bf16.h>

// ---------------------------------------------------------------------------
// GNN Residual Feature Extractor
//   x = embed(type features)                       [N,32]
//   x1 = gcn(x, W1)+b1                             [N,64]
//   h  = relu(gcn(relu(x1),W2)+b2)                 [N,128]
//   h  = relu(gcn(h,W3)+b3) + x1                   [N,64]
//   out = segment_mean(h, batch)                   [100,64]
// gcn aggregation commutes with weight multiply; aggregate on narrow side.
//
// CSR build is bucketed: bucket = dst>>5 (32 nodes), cells = (bucket, blkgrp)
// so scatter writes are sequential per cell -> L2 lines fill before eviction
// (old direct fill: 194 MB write-back for 12.8 MB of data, 280 us).
// ---------------------------------------------------------------------------

#define THREADS 256
#define EPB 8192         // edges per block for cellhist/scatter (must match!)
#define NGRP 8           // write groups (~XCDs); cell = bucket*NGRP + (blk&7)

// ---------------- stage A: per-(bucket,group) histogram ----------------
__global__ __launch_bounds__(THREADS)
void k_cellhist(const int* __restrict__ dst, int* __restrict__ cellcnt,
                int nb, int e) {
    extern __shared__ int h[];
    int t = threadIdx.x;
    for (int i = t; i < nb; i += THREADS) h[i] = 0;
    __syncthreads();
    int base = blockIdx.x * EPB;
    int lim = min(base + EPB, e);
    for (int i = base + t; i < lim; i += THREADS)
        atomicAdd(&h[dst[i] >> 5], 1);
    __syncthreads();
    int g = blockIdx.x & (NGRP - 1);
    for (int i = t; i < nb; i += THREADS)
        if (h[i]) atomicAdd(&cellcnt[i * NGRP + g], h[i]);
}

// ---------------- scan (3 kernels, generic over n) ----------------
__global__ __launch_bounds__(THREADS)
void k_block_sums(const int* __restrict__ cnt, int* __restrict__ bsums, int n) {
    __shared__ int lds[THREADS];
    int i = blockIdx.x * THREADS + threadIdx.x;
    lds[threadIdx.x] = (i < n) ? cnt[i] : 0;
    __syncthreads();
    for (int off = THREADS / 2; off > 0; off >>= 1) {
        if (threadIdx.x < off) lds[threadIdx.x] += lds[threadIdx.x + off];
        __syncthreads();
    }
    if (threadIdx.x == 0) bsums[blockIdx.x] = lds[0];
}

__global__ __launch_bounds__(512)
void k_scan_bsums(int* __restrict__ bsums, int nblk) {
    __shared__ int lds[512];
    int t = threadIdx.x;
    int v = (t < nblk) ? bsums[t] : 0;
    lds[t] = v;
    __syncthreads();
    for (int off = 1; off < 512; off <<= 1) {
        int a = (t >= off) ? lds[t - off] : 0;
        __syncthreads();
        lds[t] += a;
        __syncthreads();
    }
    if (t < nblk) bsums[t] = lds[t] - v;  // exclusive
}

__global__ __launch_bounds__(THREADS)
void k_scan_final(const int* __restrict__ cnt, const int* __restrict__ bexcl,
                  int* __restrict__ ptr, int* __restrict__ cursor,
                  int n, int e_total) {
    __shared__ int lds[THREADS];
    int t = threadIdx.x;
    int i = blockIdx.x * THREADS + t;
    int v = (i < n) ? cnt[i] : 0;
    lds[t] = v;
    __syncthreads();
    for (int off = 1; off < THREADS; off <<= 1) {
        int a = (t >= off) ? lds[t - off] : 0;
        __syncthreads();
        lds[t] += a;
        __syncthreads();
    }
    if (i < n) {
        int excl = bexcl[blockIdx.x] + lds[t] - v;
        ptr[i] = excl;
        cursor[i] = excl;
    }
    if (i == 0) ptr[n] = e_total;
}

// ---------------- stage B: scatter edges into cell-sorted order ----------------
__global__ __launch_bounds__(THREADS)
void k_scatter(const int* __restrict__ src, const int* __restrict__ dst,
               int* __restrict__ cellcur, int2* __restrict__ pairs, int e) {
    int base = blockIdx.x * EPB;
    int lim = min(base + EPB, e);
    int g = blockIdx.x & (NGRP - 1);
    for (int i = base + threadIdx.x; i < lim; i += THREADS) {
        int s = src[i], d = dst[i];
        int pos = atomicAdd(&cellcur[(d >> 5) * NGRP + g], 1);
        pairs[pos] = make_int2(s, d);
    }
}

// ---------------- stage C: per-bucket CSR finalize (rowptr, dinv, srcs) -------
__global__ __launch_bounds__(THREADS)
void k_bucket_csr(const int2* __restrict__ pairs, const int* __restrict__ cellptr,
                  int* __restrict__ rowptr, float* __restrict__ dinv,
                  int* __restrict__ srcs, int n, int e) {
    __shared__ int lcnt[32];
    __shared__ int lcur[32];
    int b = blockIdx.x;
    int t = threadIdx.x;
    int e0 = cellptr[b * NGRP], e1 = cellptr[b * NGRP + NGRP];
    int nb0 = b << 5;
    if (t < 32) lcnt[t] = 0;
    __syncthreads();
    for (int j = e0 + t; j < e1; j += THREADS)
        atomicAdd(&lcnt[pairs[j].y - nb0], 1);
    __syncthreads();
    if (t == 0) {
        int run = e0;
        for (int i = 0; i < 32; ++i) { int c = lcnt[i]; lcur[i] = run; run += c; }
    }
    __syncthreads();
    if (t < 32) {
        int node = nb0 + t;
        if (node < n) {
            rowptr[node] = lcur[t];
            dinv[node] = rsqrtf((float)lcnt[t] + 1.0f);
        }
    }
    if (b == gridDim.x - 1 && t == 0) rowptr[n] = e;
    __syncthreads();
    for (int j = e0 + t; j < e1; j += THREADS) {
        int2 p = pairs[j];
        int pos = atomicAdd(&lcur[p.y - nb0], 1);
        srcs[pos] = p.x;
    }
}

// ---------------- embedding: x[idx[r]] = f[r] @ W + b ----------------
template <int K>
__global__ __launch_bounds__(THREADS)
void k_embed(const float* __restrict__ f, const float* __restrict__ W,
             const float* __restrict__ b, const int* __restrict__ idx,
             int rows, float* __restrict__ x) {
    int g = blockIdx.x * THREADS + threadIdx.x;
    int r = g >> 5, c = g & 31;
    if (r >= rows) return;
    float a = b[c];
#pragma unroll
    for (int k = 0; k < K; ++k) a += f[r * K + k] * W[k * 32 + c];
    x[(size_t)idx[r] * 32 + c] = a;
}

// ---------------- gather aggregation ----------------
// out[i] = dv_i * ( dv_i * t(tbl[i]) + sum_j dinv[s_j] * t(tbl[s_j]) )
// t() = optional relu on read. Optional epilogue: +bias, relu, +resid.
template <int C, bool INRELU, bool HASBIAS, bool OUTRELU, bool HASRES>
__global__ __launch_bounds__(THREADS)
void k_gather(const float* __restrict__ tbl, const int* __restrict__ rowptr,
              const int* __restrict__ srcs, const float* __restrict__ dinv,
              const float* __restrict__ bias, const float* __restrict__ resid,
              float* __restrict__ out, int n) {
    int gt = blockIdx.x * THREADS + threadIdx.x;
    int node = gt >> 6;
    int lane = threadIdx.x & 63;
    if (node >= n) return;
    float dv = dinv[node];
    int beg = rowptr[node], end = rowptr[node + 1];

    if (C == 64) {
        float xv = tbl[(size_t)node * 64 + lane];
        if (INRELU) xv = fmaxf(xv, 0.f);
        float acc = dv * xv;
        int j = beg;
        for (; j + 4 <= end; j += 4) {
            int s0 = srcs[j], s1 = srcs[j + 1], s2 = srcs[j + 2], s3 = srcs[j + 3];
            float d0 = dinv[s0], d1 = dinv[s1], d2 = dinv[s2], d3 = dinv[s3];
            float v0 = tbl[(size_t)s0 * 64 + lane];
            float v1 = tbl[(size_t)s1 * 64 + lane];
            float v2 = tbl[(size_t)s2 * 64 + lane];
            float v3 = tbl[(size_t)s3 * 64 + lane];
            if (INRELU) {
                v0 = fmaxf(v0, 0.f); v1 = fmaxf(v1, 0.f);
                v2 = fmaxf(v2, 0.f); v3 = fmaxf(v3, 0.f);
            }
            acc += d0 * v0; acc += d1 * v1; acc += d2 * v2; acc += d3 * v3;
        }
        for (; j < end; ++j) {
            int s = srcs[j];
            float v = tbl[(size_t)s * 64 + lane];
            if (INRELU) v = fmaxf(v, 0.f);
            acc += dinv[s] * v;
        }
        float r = dv * acc;
        if (HASBIAS) r += bias[lane];
        if (OUTRELU) r = fmaxf(r, 0.f);
        if (HASRES) r += resid[(size_t)node * 64 + lane];
        out[(size_t)node * 64 + lane] = r;
    } else {  // C == 32 : two half-waves take alternate edges
        int col = lane & 31, half = lane >> 5;
        float acc = 0.f;
        for (int j = beg + half; j < end; j += 2) {
            int s = srcs[j];
            float v = tbl[(size_t)s * 32 + col];
            if (INRELU) v = fmaxf(v, 0.f);
            acc += dinv[s] * v;
        }
        acc += __shfl_down(acc, 32, 64);
        if (half == 0) {
            float xv = tbl[(size_t)node * 32 + col];
            if (INRELU) xv = fmaxf(xv, 0.f);
            float r = dv * (acc + dv * xv);
            if (HASBIAS) r += bias[col];
            if (OUTRELU) r = fmaxf(r, 0.f);
            if (HASRES) r += resid[(size_t)node * 32 + col];
            out[(size_t)node * 32 + col] = r;
        }
    }
}

// ---------------- dense matmul: out[N,FOUT] = in[N,FIN] @ W + b ----------------
// thread-per-row; W^T staged in LDS, broadcast float4 reads; x row in registers.
template <int FIN, int FOUT, bool HASBIAS, bool OUTRELU>
__global__ __launch_bounds__(THREADS)
void k_mm(const float* __restrict__ xin, const float* __restrict__ W,
          const float* __restrict__ bias, float* __restrict__ out, int nrows) {
    constexpr int FINQ = FIN / 4;
    __shared__ float wlds[FOUT * FIN];
    int tid = threadIdx.x;
    for (int i = tid; i < FIN * FOUT; i += THREADS) {
        int k = i / FOUT, c = i % FOUT;
        wlds[c * FIN + k] = W[i];  // store W^T
    }
    __syncthreads();
    int row = blockIdx.x * THREADS + tid;
    if (row >= nrows) return;

    float4 xreg[FINQ];
    const float4* xr = reinterpret_cast<const float4*>(xin + (size_t)row * FIN);
#pragma unroll
    for (int q = 0; q < FINQ; ++q) xreg[q] = xr[q];

    const float4* w4 = reinterpret_cast<const float4*>(wlds);
    for (int c0 = 0; c0 < FOUT; c0 += 4) {
        float a0 = HASBIAS ? bias[c0 + 0] : 0.f;
        float a1 = HASBIAS ? bias[c0 + 1] : 0.f;
        float a2 = HASBIAS ? bias[c0 + 2] : 0.f;
        float a3 = HASBIAS ? bias[c0 + 3] : 0.f;
#pragma unroll
        for (int q = 0; q < FINQ; ++q) {
            float4 xv = xreg[q];
            float4 w0 = w4[(c0 + 0) * FINQ + q];
            float4 w1 = w4[(c0 + 1) * FINQ + q];
            float4 w2 = w4[(c0 + 2) * FINQ + q];
            float4 w3 = w4[(c0 + 3) * FINQ + q];
            a0 += xv.x * w0.x + xv.y * w0.y + xv.z * w0.z + xv.w * w0.w;
            a1 += xv.x * w1.x + xv.y * w1.y + xv.z * w1.z + xv.w * w1.w;
            a2 += xv.x * w2.x + xv.y * w2.y + xv.z * w2.z + xv.w * w2.w;
            a3 += xv.x * w3.x + xv.y * w3.y + xv.z * w3.z + xv.w * w3.w;
        }
        if (OUTRELU) {
            a0 = fmaxf(a0, 0.f); a1 = fmaxf(a1, 0.f);
            a2 = fmaxf(a2, 0.f); a3 = fmaxf(a3, 0.f);
        }
        float4 o = {a0, a1, a2, a3};
        *reinterpret_cast<float4*>(out + (size_t)row * FOUT + c0) = o;
    }
}

// ---------------- segment mean pool ----------------
__global__ __launch_bounds__(THREADS)
void k_pool(const float* __restrict__ h, const int* __restrict__ batch,
            float* __restrict__ sums, float* __restrict__ cnts, int n) {
    int c = threadIdx.x & 63;
    int rq = threadIdx.x >> 6;  // 0..3
    int r0 = blockIdx.x * THREADS;
    int rend = min(r0 + THREADS, n);
    int curg = -1;
    float acc = 0.f, cacc = 0.f;
    for (int r = r0 + rq; r < rend; r += 4) {
        int g = batch[r];
        if (g != curg) {
            if (curg >= 0) {
                atomicAdd(&sums[(size_t)curg * 64 + c], acc);
                if (c == 0) atomicAdd(&cnts[curg], cacc);
            }
            curg = g; acc = 0.f; cacc = 0.f;
        }
        acc += h[(size_t)r * 64 + c];
        cacc += 1.f;
    }
    if (curg >= 0) {
        atomicAdd(&sums[(size_t)curg * 64 + c], acc);
        if (c == 0) atomicAdd(&cnts[curg], cacc);
    }
}

__global__ __launch_bounds__(THREADS)
void k_div(const float* __restrict__ sums, const float* __restrict__ cnts,
           float* __restrict__ out, int total) {
    int i = blockIdx.x * THREADS + threadIdx.x;
    if (i < total) out[i] = sums[i] / cnts[i >> 6];
}

// ---------------------------------------------------------------------------
static inline size_t alignup(size_t v) { return (v + 255) & ~(size_t)255; }

extern "C" void kernel_launch(void* const* d_in, const int* in_sizes, int n_in,
                              void* d_out, int out_size, void* d_ws, size_t ws_size,
                              hipStream_t stream) {
    const float* ev_f  = (const float*)d_in[0];
    const float* cs_f  = (const float*)d_in[1];
    const float* tr_f  = (const float*)d_in[2];
    const float* env_f = (const float*)d_in[3];
    const int*   ei    = (const int*)d_in[4];
    const int*   ev_i  = (const int*)d_in[5];
    const int*   cs_i  = (const int*)d_in[6];
    const int*   tr_i  = (const int*)d_in[7];
    const int*   env_i = (const int*)d_in[8];
    const int*   batch = (const int*)d_in[9];
    const float* W_ev = (const float*)d_in[10]; const float* b_ev = (const float*)d_in[11];
    const float* W_cs = (const float*)d_in[12]; const float* b_cs = (const float*)d_in[13];
    const float* W_tr = (const float*)d_in[14]; const float* b_tr = (const float*)d_in[15];
    const float* W_env= (const float*)d_in[16]; const float* b_env= (const float*)d_in[17];
    const float* W1 = (const float*)d_in[18]; const float* b1 = (const float*)d_in[19];
    const float* W2 = (const float*)d_in[20]; const float* b2 = (const float*)d_in[21];
    const float* W3 = (const float*)d_in[22]; const float* b3 = (const float*)d_in[23];

    const int E_ = in_sizes[4] / 2;
    const int N_ = in_sizes[9];
    const int n_ev  = in_sizes[5];
    const int n_cs  = in_sizes[6];
    const int n_tr  = in_sizes[7];
    const int n_env = in_sizes[8];
    const int ngr   = out_size / 64;  // 100 graphs

    const int* e_src = ei;
    const int* e_dst = ei + E_;

    const int NB    = (N_ + 31) >> 5;      // 3125 buckets of 32 nodes
    const int NCELL = NB * NGRP;           // 25000 cells

    // ---- workspace carve-up ----
    char* p = (char*)d_ws;
    int*   cellcnt = (int*)p;   p += alignup((size_t)NCELL * 4);
    int*   cellptr = (int*)p;   p += alignup(((size_t)NCELL + 1) * 4);
    int*   cellcur = (int*)p;   p += alignup((size_t)NCELL * 4);
    int*   bsums   = (int*)p;   p += alignup((size_t)512 * 4);
    int*   rowptr  = (int*)p;   p += alignup(((size_t)N_ + 1) * 4);
    float* dinv    = (float*)p; p += alignup((size_t)N_ * 4);
    int*   srcs    = (int*)p;   p += alignup((size_t)E_ * 4);
    float* x       = (float*)p; p += alignup((size_t)N_ * 32 * 4);
    float* x1      = (float*)p; p += alignup((size_t)N_ * 64 * 4);
    float* bufB    = (float*)p; p += alignup((size_t)N_ * 64 * 4);
    float* bufA    = (float*)p; p += alignup((size_t)N_ * 128 * 4);
    float* sums    = (float*)p; p += alignup((size_t)ngr * 64 * 4);
    float* cnts    = (float*)p; p += alignup((size_t)ngr * 4);

    // pairs (E int2 = 25.6 MB) aliases bufA (51.2 MB): dead before conv2 writes bufA
    int2* pairs = (int2*)bufA;

    const int nblk   = (N_ + THREADS - 1) / THREADS;
    const int cblk   = (NCELL + THREADS - 1) / THREADS;            // 98
    const int eblk_p = (E_ + EPB - 1) / EPB;                       // 391
    const int gblk   = ((size_t)N_ * 64 + THREADS - 1) / THREADS;  // wave per node

    // ---- zero accumulated buffers (fresh every call) ----
    hipMemsetAsync(cellcnt, 0, (size_t)NCELL * 4, stream);
    hipMemsetAsync(sums, 0, (size_t)ngr * 64 * 4, stream);
    hipMemsetAsync(cnts, 0, (size_t)ngr * 4, stream);

    // ---- bucketed CSR build ----
    k_cellhist<<<eblk_p, THREADS, (size_t)NB * 4, stream>>>(e_dst, cellcnt, NB, E_);
    k_block_sums<<<cblk, THREADS, 0, stream>>>(cellcnt, bsums, NCELL);
    k_scan_bsums<<<1, 512, 0, stream>>>(bsums, cblk);
    k_scan_final<<<cblk, THREADS, 0, stream>>>(cellcnt, bsums, cellptr, cellcur, NCELL, E_);
    k_scatter<<<eblk_p, THREADS, 0, stream>>>(e_src, e_dst, cellcur, pairs, E_);
    k_bucket_csr<<<NB, THREADS, 0, stream>>>(pairs, cellptr, rowptr, dinv, srcs, N_, E_);

    // ---- embeddings -> x [N,32] ----
    k_embed<6><<<((size_t)n_ev  * 32 + THREADS - 1) / THREADS, THREADS, 0, stream>>>(ev_f,  W_ev,  b_ev,  ev_i,  n_ev,  x);
    k_embed<4><<<((size_t)n_cs  * 32 + THREADS - 1) / THREADS, THREADS, 0, stream>>>(cs_f,  W_cs,  b_cs,  cs_i,  n_cs,  x);
    k_embed<2><<<((size_t)n_tr  * 32 + THREADS - 1) / THREADS, THREADS, 0, stream>>>(tr_f,  W_tr,  b_tr,  tr_i,  n_tr,  x);
    k_embed<5><<<((size_t)n_env * 32 + THREADS - 1) / THREADS, THREADS, 0, stream>>>(env_f, W_env, b_env, env_i, n_env, x);

    // ---- conv1: agg(x) @ W1 + b1 -> x1 ----
    k_gather<32, false, false, false, false><<<gblk, THREADS, 0, stream>>>(
        x, rowptr, srcs, dinv, nullptr, nullptr, bufB, N_);
    k_mm<32, 64, true, false><<<nblk, THREADS, 0, stream>>>(bufB, W1, b1, x1, N_);

    // ---- conv2: relu( agg(relu(x1)) @ W2 + b2 ) -> bufA [N,128] ----
    k_gather<64, true, false, false, false><<<gblk, THREADS, 0, stream>>>(
        x1, rowptr, srcs, dinv, nullptr, nullptr, bufB, N_);
    k_mm<64, 128, true, true><<<nblk, THREADS, 0, stream>>>(bufB, W2, b2, bufA, N_);

    // ---- conv3: relu( agg(bufA @ W3) + b3 ) + x1 -> bufA [N,64] ----
    k_mm<128, 64, false, false><<<nblk, THREADS, 0, stream>>>(bufA, W3, nullptr, bufB, N_);
    k_gather<64, false, true, true, true><<<gblk, THREADS, 0, stream>>>(
        bufB, rowptr, srcs, dinv, b3, x1, bufA, N_);

    // ---- pool ----
    k_pool<<<nblk, THREADS, 0, stream>>>(bufA, batch, sums, cnts, N_);
    k_div<<<(out_size + THREADS - 1) / THREADS, THREADS, 0, stream>>>(sums, cnts, (float*)d_out, out_size);
}